// Round 1
// baseline (1455.648 us; speedup 1.0000x reference)
//
#include <hip/hip_runtime.h>
#include <stdint.h>

// HistoryEncoder: unique (x,t) pairs -> grouped-mean user emb -> concat -> GEMM.
// Sort-free unique via dense key-space (16.8M) counting + rank scan.

#define N_EVENTS 400000
#define N_LOCS_ 100000
#define N_TIMES_ 168
#define NK (N_LOCS_ * N_TIMES_)            // 16,800,000 keys
#define D_LOC_ 64
#define D_TIME_ 32
#define NCOLS 256                          // 2*N_HIDDEN
#define SCAN_KEYS 4096
#define NB ((NK + SCAN_KEYS - 1) / SCAN_KEYS)   // 4102 scan blocks
#define NB_AL 4104                         // padded for alignment
#define SENTINEL 0xFFFFFFFFu

typedef unsigned int uint;

// ---- K1: histogram of keys ----
__global__ void k1_count(const int* __restrict__ x, const int* __restrict__ t,
                         uint* __restrict__ C) {
  int i = blockIdx.x * 256 + threadIdx.x;
  if (i < N_EVENTS) {
    uint key = (uint)x[i] * (uint)N_TIMES_ + (uint)t[i];
    atomicAdd(&C[key], 1u);
  }
}

// ---- K2a: per-4096-key-block count of occupied keys ----
__global__ void k2a_blockcount(const uint* __restrict__ C, uint* __restrict__ blockCnt) {
  __shared__ uint s[256];
  int tid = threadIdx.x;
  size_t base = (size_t)blockIdx.x * SCAN_KEYS + (size_t)tid * 16;
  uint c = 0;
#pragma unroll
  for (int i = 0; i < 16; ++i) {
    size_t k = base + i;
    if (k < (size_t)NK) c += (C[k] > 0u) ? 1u : 0u;
  }
  s[tid] = c; __syncthreads();
  for (int d = 128; d > 0; d >>= 1) { if (tid < d) s[tid] += s[tid + d]; __syncthreads(); }
  if (tid == 0) blockCnt[blockIdx.x] = s[0];
}

// ---- K2b: exclusive scan of blockCnt (single block, 256 threads) ----
__global__ void k2b_scan(const uint* __restrict__ blockCnt, uint* __restrict__ blockOff,
                         uint* __restrict__ d_nuniq) {
  __shared__ uint wsum[4];
  int tid = threadIdx.x; int lane = tid & 63; int w = tid >> 6;
  uint carry = 0;
  for (int base = 0; base < NB; base += 256) {
    int i = base + tid;
    uint v = (i < NB) ? blockCnt[i] : 0u;
    uint incl = v;
#pragma unroll
    for (int d = 1; d < 64; d <<= 1) { uint tt = __shfl_up(incl, d); if (lane >= d) incl += tt; }
    if (lane == 63) wsum[w] = incl;
    __syncthreads();
    uint woff = 0;
    for (int k = 0; k < w; ++k) woff += wsum[k];
    uint total = wsum[0] + wsum[1] + wsum[2] + wsum[3];
    if (i < NB) blockOff[i] = carry + woff + (incl - v);
    carry += total;
    __syncthreads();
  }
  if (tid == 0) *d_nuniq = carry;
}

// ---- K3: assign ranks; build key_of_rank / cnt_of_rank; C[key] := rank ----
__global__ void k3_rank(uint* __restrict__ C, const uint* __restrict__ blockOff,
                        uint* __restrict__ key_of_rank, uint* __restrict__ cnt_of_rank) {
  __shared__ uint s[256];
  int tid = threadIdx.x;
  size_t base = (size_t)blockIdx.x * SCAN_KEYS + (size_t)tid * 16;
  uint cv[16]; uint local = 0;
#pragma unroll
  for (int i = 0; i < 16; ++i) {
    size_t k = base + i;
    uint v = (k < (size_t)NK) ? C[k] : 0u;
    cv[i] = v; local += (v > 0u) ? 1u : 0u;
  }
  s[tid] = local; __syncthreads();
  for (int d = 1; d < 256; d <<= 1) {
    uint tt = (tid >= d) ? s[tid - d] : 0u;
    __syncthreads();
    s[tid] += tt;
    __syncthreads();
  }
  uint r = blockOff[blockIdx.x] + s[tid] - local;   // exclusive prefix within grid
#pragma unroll
  for (int i = 0; i < 16; ++i) {
    if (cv[i] > 0u) {
      size_t k = base + i;
      key_of_rank[r] = (uint)k;
      cnt_of_rank[r] = cv[i];
      C[k] = r;
      ++r;
    }
  }
}

// ---- K4: accumulate user-embedding sums per rank (64 lanes per event) ----
__global__ void k4_usum(const int* __restrict__ x, const int* __restrict__ t,
                        const int* __restrict__ u, const float* __restrict__ user_table,
                        const uint* __restrict__ C, float* __restrict__ usum) {
  int e = blockIdx.x * 4 + (threadIdx.x >> 6);
  int j = threadIdx.x & 63;
  uint key = (uint)x[e] * (uint)N_TIMES_ + (uint)t[e];
  uint r = C[key];
  atomicAdd(&usum[(size_t)r * 64 + j], user_table[(size_t)u[e] * 64 + j]);
}

// ---- K5: fused gather + [64rows x 160K x 256cols] fp32 GEMM per block ----
__global__ __launch_bounds__(256) void k5_gemm(
    const float* __restrict__ loc_table, const float* __restrict__ time_table,
    const float* __restrict__ W, const float* __restrict__ bias,
    const uint* __restrict__ key_of_rank, const uint* __restrict__ cnt_of_rank,
    const float* __restrict__ usum, const uint* __restrict__ d_nuniq,
    float* __restrict__ out) {
  __shared__ float WS[32][NCOLS];   // 32 KB: W K-chunk
  __shared__ float XS[64][32];      // 8 KB: X K-chunk for 64 rows
  __shared__ uint rk_key[64];
  __shared__ float rk_scale[64];

  int tid = threadIdx.x;
  uint nu = *d_nuniq;
  int rowbase = blockIdx.x * 64;

  if (tid < 64) {
    int row = rowbase + tid;
    if ((uint)row < nu) {
      rk_key[tid] = key_of_rank[row];
      uint cc = cnt_of_rank[row];
      rk_scale[tid] = 1.0f / (float)(cc > 0u ? cc : 1u);
    } else { rk_key[tid] = SENTINEL; rk_scale[tid] = 0.0f; }
  }
  // first __syncthreads in the chunk loop covers this staging

  int c = tid & 63;   // column group: cols 4c..4c+3
  int g = tid >> 6;   // row group: rows g*16 .. g*16+15
  float4 acc[16];
#pragma unroll
  for (int r = 0; r < 16; ++r) acc[r] = make_float4(0.f, 0.f, 0.f, 0.f);

  int sr = tid >> 2;         // staging row 0..63
  int j0 = (tid & 3) * 8;    // staging col offset (floats)
  int j4 = (tid & 3) * 2;    // staging float4 index

  const float4* W4 = (const float4*)W;

  for (int ch = 0; ch < 5; ++ch) {
    __syncthreads();   // protect WS/XS (and rk_* on first iter)
    // stage W chunk [32][256]
#pragma unroll
    for (int i = 0; i < 8; ++i) {
      int f = i * 256 + tid;         // 0..2047 float4 slots
      int k = f >> 6; int c4 = f & 63;
      *((float4*)&WS[k][c4 * 4]) = W4[(size_t)(ch * 32 + k) * 64 + c4];
    }
    // stage X chunk [64][32]
    {
      uint key = rk_key[sr];
      float4 va = make_float4(0.f, 0.f, 0.f, 0.f);
      float4 vb = make_float4(0.f, 0.f, 0.f, 0.f);
      if (key != SENTINEL) {
        if (ch <= 1) {
          uint xu = key / (uint)N_TIMES_;
          const float4* s4 = (const float4*)(loc_table + (size_t)xu * D_LOC_ + ch * 32);
          va = s4[j4]; vb = s4[j4 + 1];
        } else if (ch == 2) {
          uint tu = key % (uint)N_TIMES_;
          const float4* s4 = (const float4*)(time_table + (size_t)tu * D_TIME_);
          va = s4[j4]; vb = s4[j4 + 1];
        } else {
          int row = rowbase + sr;
          float sc = rk_scale[sr];
          const float4* s4 = (const float4*)(usum + (size_t)row * 64 + (ch - 3) * 32);
          va = s4[j4]; vb = s4[j4 + 1];
          va.x *= sc; va.y *= sc; va.z *= sc; va.w *= sc;
          vb.x *= sc; vb.y *= sc; vb.z *= sc; vb.w *= sc;
        }
      }
      *((float4*)&XS[sr][j0])     = va;
      *((float4*)&XS[sr][j0 + 4]) = vb;
    }
    __syncthreads();
    // compute: 4 cols x 16 rows per thread, K-chunk of 32
#pragma unroll
    for (int k4 = 0; k4 < 8; ++k4) {
      float4 w0 = *((float4*)&WS[4 * k4 + 0][c * 4]);
      float4 w1 = *((float4*)&WS[4 * k4 + 1][c * 4]);
      float4 w2 = *((float4*)&WS[4 * k4 + 2][c * 4]);
      float4 w3 = *((float4*)&WS[4 * k4 + 3][c * 4]);
#pragma unroll
      for (int r = 0; r < 16; ++r) {
        float4 xv = *((float4*)&XS[g * 16 + r][k4 * 4]);
        acc[r].x += xv.x * w0.x + xv.y * w1.x + xv.z * w2.x + xv.w * w3.x;
        acc[r].y += xv.x * w0.y + xv.y * w1.y + xv.z * w2.y + xv.w * w3.y;
        acc[r].z += xv.x * w0.z + xv.y * w1.z + xv.z * w2.z + xv.w * w3.z;
        acc[r].w += xv.x * w0.w + xv.y * w1.w + xv.z * w2.w + xv.w * w3.w;
      }
    }
  }

  // epilogue: add bias, zero padded rows, coalesced float4 stores
  float4 bv = ((const float4*)bias)[c];
  float4* out4 = (float4*)out;
#pragma unroll
  for (int r = 0; r < 16; ++r) {
    int row = rowbase + g * 16 + r;
    float4 v;
    if ((uint)row < nu) {
      v.x = acc[r].x + bv.x; v.y = acc[r].y + bv.y;
      v.z = acc[r].z + bv.z; v.w = acc[r].w + bv.w;
    } else {
      v = make_float4(0.f, 0.f, 0.f, 0.f);
    }
    out4[(size_t)row * 64 + c] = v;
  }
}

extern "C" void kernel_launch(void* const* d_in, const int* in_sizes, int n_in,
                              void* d_out, int out_size, void* d_ws, size_t ws_size,
                              hipStream_t stream) {
  const int* x = (const int*)d_in[0];
  const int* t = (const int*)d_in[1];
  const int* u = (const int*)d_in[2];
  const float* loc_table  = (const float*)d_in[3];
  const float* time_table = (const float*)d_in[4];
  const float* user_table = (const float*)d_in[5];
  const float* W    = (const float*)d_in[6];
  const float* bias = (const float*)d_in[7];
  float* out = (float*)d_out;

  // workspace layout (u32 units); total ~173 MB
  uint* C           = (uint*)d_ws;              // NK
  uint* blockCnt    = C + NK;                   // NB_AL
  uint* blockOff    = blockCnt + NB_AL;         // NB_AL
  uint* d_nuniq     = blockOff + NB_AL;         // 4 (padded)
  uint* key_of_rank = d_nuniq + 4;              // N_EVENTS
  uint* cnt_of_rank = key_of_rank + N_EVENTS;   // N_EVENTS
  float* usum       = (float*)(cnt_of_rank + N_EVENTS);  // N_EVENTS*64 (16B-aligned)

  hipMemsetAsync(C, 0, (size_t)NK * sizeof(uint), stream);
  hipMemsetAsync(usum, 0, (size_t)N_EVENTS * 64 * sizeof(float), stream);

  k1_count<<<(N_EVENTS + 255) / 256, 256, 0, stream>>>(x, t, C);
  k2a_blockcount<<<NB, 256, 0, stream>>>(C, blockCnt);
  k2b_scan<<<1, 256, 0, stream>>>(blockCnt, blockOff, d_nuniq);
  k3_rank<<<NB, 256, 0, stream>>>(C, blockOff, key_of_rank, cnt_of_rank);
  k4_usum<<<N_EVENTS / 4, 256, 0, stream>>>(x, t, u, user_table, C, usum);
  k5_gemm<<<N_EVENTS / 64, 256, 0, stream>>>(loc_table, time_table, W, bias,
                                             key_of_rank, cnt_of_rank, usum, d_nuniq, out);
}